// Round 7
// baseline (708.445 us; speedup 1.0000x reference)
//
#include <hip/hip_runtime.h>
#include <hip/hip_bf16.h>

#define NN   100000
#define EE   3200000
#define HH   32
#define BB   128
#define KMAX 96
#define NBKT 256         // dst buckets
#define BSPAN 391        // ceil(NN/NBKT)
#define WSPAN 98         // csr-build window (4 windows/bucket)
#define EBLK 256         // edge-chunk blocks
#define CHUNK 12500      // EE / EBLK exactly
#define NSPLIT 50000     // src-range split: pass A gathers src<NSPLIT (3.2 MB q window)

// ws layout (bytes), 16B-aligned, non-overlapping (~72 MB)
static constexpr size_t Q_OFF      = 0;           // N*32 bf16 = 6.4 MB
static constexpr size_t AGG_OFF    = 6400000;     // N*32 f32 = 12.8 MB
static constexpr size_t H_OFF      = 19200000;    // N*32 f32 = 12.8 MB
static constexpr size_t EPACK_OFF  = 32000000;    // EE int = 12.8 MB
static constexpr size_t SRCLO_OFF  = 44800000;    // EE int (sparse, lo sub-lists)
static constexpr size_t SRCHI_OFF  = 57600000;    // EE int (sparse, hi sub-lists)
static constexpr size_t OFF_OFF    = 70400000;    // (N+1) int
static constexpr size_t CNTS_OFF   = 70900000;    // N int: dlo | dhi<<16
static constexpr size_t HIST_OFF   = 71400000;    // EBLK*NBKT int = 256 KB
static constexpr size_t START_OFF  = 71700000;    // EBLK*NBKT int = 256 KB
static constexpr size_t BBASE_OFF  = 72000000;    // (NBKT+1) int
static constexpr size_t STATS_OFF  = 72010000;    // 4 layers x 64 f32
static constexpr size_t POOLED_OFF = 72011024;    // B*32 f32
static constexpr size_t PCNT_OFF   = 72027408;    // B f32
static constexpr size_t ZERO_OFF   = STATS_OFF;   // stats+pooled+pcnt one memset
static constexpr size_t ZERO_BYTES = 17920;

// ---- K1: per-block LDS histogram of dst buckets
__global__ __launch_bounds__(256) void hist_kernel(const int* __restrict__ ei,
                                                   int* __restrict__ hist) {
    __shared__ int lh[NBKT];
    int tid = threadIdx.x, blk = blockIdx.x;
    for (int i = tid; i < NBKT; i += 256) lh[i] = 0;
    __syncthreads();
    int e0 = blk * CHUNK;
    for (int e = e0 + tid; e < e0 + CHUNK; e += 256) {
        int d = ei[EE + e];
        atomicAdd(&lh[d / BSPAN], 1);
    }
    __syncthreads();
    for (int i = tid; i < NBKT; i += 256) hist[blk * NBKT + i] = lh[i];
}

// ---- K2 (fused totals+scan+starts): 1 block, thread t owns bucket t
__global__ __launch_bounds__(NBKT) void bucket_scan_kernel(const int* __restrict__ hist,
                                                           int* __restrict__ bbase,
                                                           int* __restrict__ start) {
    __shared__ int sm[NBKT];
    int t = threadIdx.x;
    int mine = 0;
    for (int blk = 0; blk < EBLK; blk++) mine += hist[blk * NBKT + t];
    sm[t] = mine;
    __syncthreads();
    for (int off = 1; off < NBKT; off <<= 1) {
        int v = (t >= off) ? sm[t - off] : 0;
        __syncthreads();
        sm[t] += v;
        __syncthreads();
    }
    int base = sm[t] - mine;   // exclusive
    bbase[t] = base;
    if (t == NBKT - 1) bbase[NBKT] = sm[t];
    int run = base;
    for (int blk = 0; blk < EBLK; blk++) {
        start[blk * NBKT + t] = run;
        run += hist[blk * NBKT + t];
    }
}

// ---- K3: scatter packed (src | dstoff<<17) into bucket-grouped array
__global__ __launch_bounds__(256) void scatter_kernel(const int* __restrict__ ei,
                                                      const int* __restrict__ start,
                                                      int* __restrict__ epack) {
    __shared__ int loff[NBKT];
    int tid = threadIdx.x, blk = blockIdx.x;
    for (int i = tid; i < NBKT; i += 256) loff[i] = start[blk * NBKT + i];
    __syncthreads();
    int e0 = blk * CHUNK;
    for (int e = e0 + tid; e < e0 + CHUNK; e += 256) {
        int s = ei[e];
        int d = ei[EE + e];
        int b = d / BSPAN;
        int slot = atomicAdd(&loff[b], 1);
        epack[slot] = s | ((d - b * BSPAN) << 17);
    }
}

// ---- K4: compact CSR build, split by src range. Per 98-node window: LDS scatter
// by dst, per-node partition into lo (<NSPLIT) then hi, write exact offsets +
// packed counts + dense srcs_lo/srcs_hi (shared offset base, gap-free per list).
__global__ __launch_bounds__(256) void csr_split_kernel(const int* __restrict__ epack,
                                                        const int* __restrict__ bbase,
                                                        int* __restrict__ off,
                                                        int* __restrict__ cnts,
                                                        int* __restrict__ srcs_lo,
                                                        int* __restrict__ srcs_hi) {
    __shared__ int lcnt[WSPAN];
    __shared__ int lbase[WSPAN + 1];
    __shared__ int dlo_s[WSPAN];
    __shared__ int lcsr[WSPAN * KMAX];    // 37632 B
    __shared__ int lcsr2[WSPAN * KMAX];   // 37632 B (partitioned)
    __shared__ int sh_before;
    int blk = blockIdx.x;
    int b = blk >> 2, w = blk & 3;
    int base = b * BSPAN;
    int span = NN - base;
    if (span <= 0) return;
    if (span > BSPAN) span = BSPAN;
    int wstart = w * WSPAN;
    if (wstart >= span) return;
    int wend = min(wstart + WSPAN, span);
    int wn = wend - wstart;
    int tid = threadIdx.x;
    if (tid == 0) sh_before = 0;
    for (int i = tid; i < wn; i += 256) lcnt[i] = 0;
    __syncthreads();
    int p0 = bbase[b], p1 = bbase[b + 1];
    int nbefore = 0;
    for (int i = p0 + tid; i < p1; i += 256) {
        int wd = epack[i];
        int ld = wd >> 17;
        if (ld < wstart) nbefore++;
        else if (ld < wend) {
            int slot = atomicAdd(&lcnt[ld - wstart], 1);
            if (slot < KMAX) lcsr[(ld - wstart) * KMAX + slot] = wd & 0x1FFFF;
        }
    }
    atomicAdd(&sh_before, nbefore);
    __syncthreads();
    if (tid == 0) {
        int run = 0;
        for (int i = 0; i < wn; i++) { lbase[i] = run; run += lcnt[i]; }
        lbase[wn] = run;
    }
    // per-node partition lo-first into lcsr2 (1 thread per node)
    for (int i = tid; i < wn; i += 256) {
        int d = min(lcnt[i], KMAX);
        int cl = 0;
        for (int k = 0; k < d; k++) {
            int v = lcsr[i * KMAX + k];
            if (v < NSPLIT) lcsr2[i * KMAX + cl++] = v;
        }
        dlo_s[i] = cl;
        for (int k = 0; k < d; k++) {
            int v = lcsr[i * KMAX + k];
            if (v >= NSPLIT) lcsr2[i * KMAX + cl++] = v;
        }
    }
    __syncthreads();
    int w0 = p0 + sh_before;
    for (int i = tid; i < wn; i += 256) {
        off[base + wstart + i] = w0 + lbase[i];
        int d = min(lcnt[i], KMAX);
        cnts[base + wstart + i] = dlo_s[i] | ((d - dlo_s[i]) << 16);
    }
    if (base + wend == NN && tid == 0) off[NN] = w0 + lbase[wn];
    int m = lbase[wn];
    for (int j = tid; j < m; j += 256) {
        int lo = 0, hi = wn - 1;
        while (lo < hi) {
            int mid = (lo + hi + 1) >> 1;
            if (lbase[mid] <= j) lo = mid; else hi = mid - 1;
        }
        int sl = j - lbase[lo];
        int d = min(lcnt[lo], KMAX);
        if (sl >= d) continue;
        int dl = dlo_s[lo];
        int v = lcsr2[lo * KMAX + sl];
        if (sl < dl) srcs_lo[w0 + j] = v;
        else         srcs_hi[w0 + j - dl] = v;
    }
}

__device__ __forceinline__ unsigned bf16rn(float f) {
    unsigned b = __float_as_uint(f);
    return (b + 0x7fffu + ((b >> 16) & 1u)) >> 16;   // RNE
}

__device__ __forceinline__ void acc_row(float* a, uint4 v) {
    a[0] += __uint_as_float(v.x << 16);
    a[1] += __uint_as_float(v.x & 0xffff0000u);
    a[2] += __uint_as_float(v.y << 16);
    a[3] += __uint_as_float(v.y & 0xffff0000u);
    a[4] += __uint_as_float(v.z << 16);
    a[5] += __uint_as_float(v.z & 0xffff0000u);
    a[6] += __uint_as_float(v.w << 16);
    a[7] += __uint_as_float(v.w & 0xffff0000u);
}

// ---- projection q(bf16, 64 B rows) = BN(h) @ w1; BN affine computed in-kernel
// from prev layer's raw stats (FIN==32). FIN==128 (layer 0): no BN.
template <int FIN>
__global__ __launch_bounds__(256) void proj_kernel(const float* __restrict__ hin,
                                                   const float* __restrict__ w1,
                                                   const float* __restrict__ stats_prev,
                                                   const float* __restrict__ gamma,
                                                   const float* __restrict__ beta,
                                                   uint4* __restrict__ q4) {
    __shared__ float sa[32], sc[32];
    int tid = threadIdx.x;
    if constexpr (FIN == 32) {
        if (tid < 32) {
            float mean = stats_prev[tid] * (1.0f / NN);
            float var  = fmaxf(stats_prev[32 + tid] * (1.0f / NN) - mean * mean, 0.f);
            float av = gamma[tid] * rsqrtf(var + 1e-5f);
            sa[tid] = av;
            sc[tid] = beta[tid] - mean * av;
        }
        __syncthreads();
    }
    int n = blockIdx.x * 256 + tid;
    if (n >= NN) return;
    float acc[32];
#pragma unroll
    for (int c = 0; c < 32; c++) acc[c] = 0.f;
    const float4* h4 = (const float4*)(hin + (size_t)n * FIN);
    for (int jj = 0; jj < FIN; jj += 32) {
        float hv[32];
#pragma unroll
        for (int k = 0; k < 8; k++) {
            float4 v = h4[jj / 4 + k];
            hv[4 * k] = v.x; hv[4 * k + 1] = v.y; hv[4 * k + 2] = v.z; hv[4 * k + 3] = v.w;
        }
        if constexpr (FIN == 32) {
#pragma unroll
            for (int j = 0; j < 32; j++) hv[j] = fmaf(hv[j], sa[j], sc[j]);
        }
#pragma unroll 4
        for (int j = 0; j < 32; j++) {
            float hvj = hv[j];
            const float* wrow = w1 + (size_t)(jj + j) * 32;
#pragma unroll
            for (int c = 0; c < 32; c++) acc[c] = fmaf(hvj, wrow[c], acc[c]);
        }
    }
#pragma unroll
    for (int k = 0; k < 4; k++) {
        uint4 u;
        u.x = bf16rn(acc[8*k+0]) | (bf16rn(acc[8*k+1]) << 16);
        u.y = bf16rn(acc[8*k+2]) | (bf16rn(acc[8*k+3]) << 16);
        u.z = bf16rn(acc[8*k+4]) | (bf16rn(acc[8*k+5]) << 16);
        u.w = bf16rn(acc[8*k+6]) | (bf16rn(acc[8*k+7]) << 16);
        q4[(size_t)n * 4 + k] = u;
    }
}

// ---- gather pass A: agg[n] = q[n] + b1 + sum q[src<NSPLIT] (hot set 3.2 MB).
// 4 lanes/node x 16 B, 8-unrolled; srcs streamed nontemporal.
__global__ __launch_bounds__(256) void gatherA_kernel(const uint4* __restrict__ q4,
                                                      const int* __restrict__ srcs,
                                                      const int* __restrict__ off,
                                                      const int* __restrict__ cnts,
                                                      const float* __restrict__ b1,
                                                      float* __restrict__ agg) {
    int t = blockIdx.x * 256 + threadIdx.x;
    int n = t >> 2;
    if (n >= NN) return;
    int p = t & 3;
    float a[8];
#pragma unroll
    for (int k = 0; k < 8; k++) a[k] = b1[p * 8 + k];
    acc_row(a, q4[(size_t)n * 4 + p]);   // self term
    int o0 = off[n];
    int d = cnts[n] & 0xffff;
    const int* lst = srcs + o0;
    int i = 0;
    for (; i + 8 <= d; i += 8) {
        int s0 = __builtin_nontemporal_load(lst + i);
        int s1 = __builtin_nontemporal_load(lst + i + 1);
        int s2 = __builtin_nontemporal_load(lst + i + 2);
        int s3 = __builtin_nontemporal_load(lst + i + 3);
        int s4 = __builtin_nontemporal_load(lst + i + 4);
        int s5 = __builtin_nontemporal_load(lst + i + 5);
        int s6 = __builtin_nontemporal_load(lst + i + 6);
        int s7 = __builtin_nontemporal_load(lst + i + 7);
        uint4 v0 = q4[(size_t)s0 * 4 + p];
        uint4 v1 = q4[(size_t)s1 * 4 + p];
        uint4 v2 = q4[(size_t)s2 * 4 + p];
        uint4 v3 = q4[(size_t)s3 * 4 + p];
        uint4 v4 = q4[(size_t)s4 * 4 + p];
        uint4 v5 = q4[(size_t)s5 * 4 + p];
        uint4 v6 = q4[(size_t)s6 * 4 + p];
        uint4 v7 = q4[(size_t)s7 * 4 + p];
        acc_row(a, v0); acc_row(a, v1); acc_row(a, v2); acc_row(a, v3);
        acc_row(a, v4); acc_row(a, v5); acc_row(a, v6); acc_row(a, v7);
    }
    for (; i < d; i++) {
        int s = __builtin_nontemporal_load(lst + i);
        acc_row(a, q4[(size_t)s * 4 + p]);
    }
    float4* ar = (float4*)(agg + (size_t)n * 32 + p * 8);
    float4 f0, f1;
    f0.x = a[0]; f0.y = a[1]; f0.z = a[2]; f0.w = a[3];
    f1.x = a[4]; f1.y = a[5]; f1.z = a[6]; f1.w = a[7];
    ar[0] = f0; ar[1] = f1;
}

// ---- gather pass B: agg[n] += sum q[src>=NSPLIT] (hot set = upper 3.2 MB).
__global__ __launch_bounds__(256) void gatherB_kernel(const uint4* __restrict__ q4,
                                                      const int* __restrict__ srcs,
                                                      const int* __restrict__ off,
                                                      const int* __restrict__ cnts,
                                                      float* __restrict__ agg) {
    int t = blockIdx.x * 256 + threadIdx.x;
    int n = t >> 2;
    if (n >= NN) return;
    int p = t & 3;
    float a[8];
#pragma unroll
    for (int k = 0; k < 8; k++) a[k] = 0.f;
    int o0 = off[n];
    int d = cnts[n] >> 16;
    const int* lst = srcs + o0;
    int i = 0;
    for (; i + 8 <= d; i += 8) {
        int s0 = __builtin_nontemporal_load(lst + i);
        int s1 = __builtin_nontemporal_load(lst + i + 1);
        int s2 = __builtin_nontemporal_load(lst + i + 2);
        int s3 = __builtin_nontemporal_load(lst + i + 3);
        int s4 = __builtin_nontemporal_load(lst + i + 4);
        int s5 = __builtin_nontemporal_load(lst + i + 5);
        int s6 = __builtin_nontemporal_load(lst + i + 6);
        int s7 = __builtin_nontemporal_load(lst + i + 7);
        uint4 v0 = q4[(size_t)s0 * 4 + p];
        uint4 v1 = q4[(size_t)s1 * 4 + p];
        uint4 v2 = q4[(size_t)s2 * 4 + p];
        uint4 v3 = q4[(size_t)s3 * 4 + p];
        uint4 v4 = q4[(size_t)s4 * 4 + p];
        uint4 v5 = q4[(size_t)s5 * 4 + p];
        uint4 v6 = q4[(size_t)s6 * 4 + p];
        uint4 v7 = q4[(size_t)s7 * 4 + p];
        acc_row(a, v0); acc_row(a, v1); acc_row(a, v2); acc_row(a, v3);
        acc_row(a, v4); acc_row(a, v5); acc_row(a, v6); acc_row(a, v7);
    }
    for (; i < d; i++) {
        int s = __builtin_nontemporal_load(lst + i);
        acc_row(a, q4[(size_t)s * 4 + p]);
    }
    float4* ar = (float4*)(agg + (size_t)n * 32 + p * 8);
    float4 g0 = ar[0], g1 = ar[1];
    g0.x += a[0]; g0.y += a[1]; g0.z += a[2]; g0.w += a[3];
    g1.x += a[4]; g1.y += a[5]; g1.z += a[6]; g1.w += a[7];
    ar[0] = g0; ar[1] = g1;
}

// ---- MLP tail: h = relu(relu(agg)@w2 + b2); accumulate raw BN stats (layer slot).
__global__ __launch_bounds__(256) void mlp_kernel(const float* __restrict__ agg,
                                                  const float* __restrict__ w2,
                                                  const float* __restrict__ b2,
                                                  float* __restrict__ r,
                                                  float* __restrict__ stats) {
    __shared__ float tile[256 * 33];
    __shared__ float ps[8 * 32];
    __shared__ float pq[8 * 32];
    int tid = threadIdx.x;
    int n = blockIdx.x * 256 + tid;
    float rc[32];
    if (n < NN) {
        float u[32];
        const float4* a4 = (const float4*)(agg + (size_t)n * 32);
#pragma unroll
        for (int k = 0; k < 8; k++) {
            float4 v = a4[k];
            u[4*k]   = fmaxf(v.x, 0.f);
            u[4*k+1] = fmaxf(v.y, 0.f);
            u[4*k+2] = fmaxf(v.z, 0.f);
            u[4*k+3] = fmaxf(v.w, 0.f);
        }
#pragma unroll
        for (int c = 0; c < 32; c++) rc[c] = b2[c];
#pragma unroll 4
        for (int j = 0; j < 32; j++) {
            float uj = u[j];
            const float* wrow = w2 + (size_t)j * 32;
#pragma unroll
            for (int c = 0; c < 32; c++) rc[c] = fmaf(uj, wrow[c], rc[c]);
        }
#pragma unroll
        for (int c = 0; c < 32; c++) rc[c] = fmaxf(rc[c], 0.f);
        float4* rr = (float4*)(r + (size_t)n * 32);
#pragma unroll
        for (int k = 0; k < 8; k++) {
            float4 v; v.x = rc[4*k]; v.y = rc[4*k+1]; v.z = rc[4*k+2]; v.w = rc[4*k+3];
            rr[k] = v;
        }
    } else {
#pragma unroll
        for (int c = 0; c < 32; c++) rc[c] = 0.f;
    }
#pragma unroll
    for (int c = 0; c < 32; c++) tile[tid * 33 + c] = rc[c];
    __syncthreads();
    {
        int c = tid & 31, rb = tid >> 5;
        float s = 0.f, sq = 0.f;
        for (int it = 0; it < 32; it++) {
            float v = tile[(rb * 32 + it) * 33 + c];
            s += v; sq += v * v;
        }
        ps[rb * 32 + c] = s; pq[rb * 32 + c] = sq;
    }
    __syncthreads();
    if (tid < 32) {
        float s = 0.f, sq = 0.f;
#pragma unroll
        for (int rb = 0; rb < 8; rb++) { s += ps[rb * 32 + tid]; sq += pq[rb * 32 + tid]; }
        atomicAdd(&stats[tid], s);
        atomicAdd(&stats[32 + tid], sq);
    }
}

// ---- pooling: segment sums of raw h3 (sorted batch -> run-length flush)
#define PR 16
__global__ __launch_bounds__(256) void pool_kernel(const float* __restrict__ h,
                                                   const int* __restrict__ batch,
                                                   float* __restrict__ pooled,
                                                   float* __restrict__ pcnt) {
    int t = blockIdx.x * 256 + threadIdx.x;
    int c = t & 31;
    int g = t >> 5;
    int r0 = g * PR;
    if (r0 >= NN) return;
    int r1 = min(r0 + PR, NN);
    int cur = batch[r0];
    float acc = 0.f, cn = 0.f;
    for (int rr = r0; rr < r1; rr++) {
        int b = batch[rr];
        if (b != cur) {
            atomicAdd(&pooled[cur * 32 + c], acc);
            if (c == 0) atomicAdd(&pcnt[cur], cn);
            acc = 0.f; cn = 0.f; cur = b;
        }
        acc += h[(size_t)rr * 32 + c];
        cn += 1.f;
    }
    atomicAdd(&pooled[cur * 32 + c], acc);
    if (c == 0) atomicAdd(&pcnt[cur], cn);
}

// ---- head: BN3 (from raw stats3) on pooled means, fc1+relu, fc2, log_softmax
__global__ __launch_bounds__(128) void head_kernel(const float* __restrict__ pooled,
                                                   const float* __restrict__ pcnt,
                                                   const float* __restrict__ stats3,
                                                   const float* __restrict__ g3,
                                                   const float* __restrict__ be3,
                                                   const float* __restrict__ fc1w,
                                                   const float* __restrict__ fc1b,
                                                   const float* __restrict__ fc2w,
                                                   const float* __restrict__ fc2b,
                                                   float* __restrict__ out) {
    __shared__ float sa[32], sc[32];
    int g = threadIdx.x;
    if (g < 32) {
        float mean = stats3[g] * (1.0f / NN);
        float var  = fmaxf(stats3[32 + g] * (1.0f / NN) - mean * mean, 0.f);
        float av = g3[g] * rsqrtf(var + 1e-5f);
        sa[g] = av;
        sc[g] = be3[g] - mean * av;
    }
    __syncthreads();
    if (g >= BB) return;
    float inv = 1.f / fmaxf(pcnt[g], 1.f);
    float xv[32];
#pragma unroll
    for (int c = 0; c < 32; c++) xv[c] = fmaf(sa[c], pooled[g * 32 + c] * inv, sc[c]);
    float u[32];
#pragma unroll 4
    for (int k = 0; k < 32; k++) {
        float s = fc1b[k];
#pragma unroll
        for (int c = 0; c < 32; c++) s = fmaf(xv[c], fc1w[c * 32 + k], s);
        u[k] = fmaxf(s, 0.f);
    }
    float l[8];
#pragma unroll
    for (int o = 0; o < 8; o++) {
        float s = fc2b[o];
#pragma unroll
        for (int k = 0; k < 32; k++) s = fmaf(u[k], fc2w[k * 8 + o], s);
        l[o] = s;
    }
    float m = l[0];
#pragma unroll
    for (int o = 1; o < 8; o++) m = fmaxf(m, l[o]);
    float se = 0.f;
#pragma unroll
    for (int o = 0; o < 8; o++) se += expf(l[o] - m);
    float lse = logf(se) + m;
#pragma unroll
    for (int o = 0; o < 8; o++) out[g * 8 + o] = l[o] - lse;
}

extern "C" void kernel_launch(void* const* d_in, const int* in_sizes, int n_in,
                              void* d_out, int out_size, void* d_ws, size_t ws_size,
                              hipStream_t stream) {
    const float* x    = (const float*)d_in[0];
    const int*   ei   = (const int*)d_in[1];
    const int*   batch= (const int*)d_in[2];
    const float* w1_0 = (const float*)d_in[3];
    const float* b1_0 = (const float*)d_in[4];
    const float* w2_0 = (const float*)d_in[5];
    const float* b2_0 = (const float*)d_in[6];
    const float* g_0  = (const float*)d_in[7];
    const float* be_0 = (const float*)d_in[8];
    const float* w1s  = (const float*)d_in[9];
    const float* b1s  = (const float*)d_in[10];
    const float* w2s  = (const float*)d_in[11];
    const float* b2s  = (const float*)d_in[12];
    const float* gs   = (const float*)d_in[13];
    const float* bes  = (const float*)d_in[14];
    const float* fc1w = (const float*)d_in[15];
    const float* fc1b = (const float*)d_in[16];
    const float* fc2w = (const float*)d_in[17];
    const float* fc2b = (const float*)d_in[18];
    float* out = (float*)d_out;

    char* ws = (char*)d_ws;
    uint4*    q4     = (uint4*)(ws + Q_OFF);
    float*    agg    = (float*)(ws + AGG_OFF);
    float*    h      = (float*)(ws + H_OFF);
    int*      epack  = (int*)(ws + EPACK_OFF);
    int*      srcs_lo= (int*)(ws + SRCLO_OFF);
    int*      srcs_hi= (int*)(ws + SRCHI_OFF);
    int*      off    = (int*)(ws + OFF_OFF);
    int*      cnts   = (int*)(ws + CNTS_OFF);
    int*      hist   = (int*)(ws + HIST_OFF);
    int*      start  = (int*)(ws + START_OFF);
    int*      bbase  = (int*)(ws + BBASE_OFF);
    float*    stats  = (float*)(ws + STATS_OFF);   // 4 slots x 64
    float*    pooled = (float*)(ws + POOLED_OFF);
    float*    pcnt   = (float*)(ws + PCNT_OFF);

    hipMemsetAsync(ws + ZERO_OFF, 0, ZERO_BYTES, stream);

    // CSR build chain
    hist_kernel<<<EBLK, 256, 0, stream>>>(ei, hist);
    bucket_scan_kernel<<<1, NBKT, 0, stream>>>(hist, bbase, start);
    scatter_kernel<<<EBLK, 256, 0, stream>>>(ei, start, epack);
    csr_split_kernel<<<NBKT * 4, 256, 0, stream>>>(epack, bbase, off, cnts, srcs_lo, srcs_hi);

    const int nblk = (NN + 255) / 256;
    const int gblk = (NN * 4 + 255) / 256;

    // layer 0 (F_IN=128, no input BN)
    proj_kernel<128><<<nblk, 256, 0, stream>>>(x, w1_0, nullptr, nullptr, nullptr, q4);
    gatherA_kernel<<<gblk, 256, 0, stream>>>(q4, srcs_lo, off, cnts, b1_0, agg);
    gatherB_kernel<<<gblk, 256, 0, stream>>>(q4, srcs_hi, off, cnts, agg);
    mlp_kernel<<<nblk, 256, 0, stream>>>(agg, w2_0, b2_0, h, stats);

    // layers 1..3, prev BN computed in proj from raw stats slot
    for (int i = 0; i < 3; i++) {
        const float* st_prev = stats + i * 64;
        proj_kernel<32><<<nblk, 256, 0, stream>>>(h, w1s + i * 1024, st_prev,
                                                  gs + i * 32, bes + i * 32, q4);
        gatherA_kernel<<<gblk, 256, 0, stream>>>(q4, srcs_lo, off, cnts, b1s + i * 32, agg);
        gatherB_kernel<<<gblk, 256, 0, stream>>>(q4, srcs_hi, off, cnts, agg);
        mlp_kernel<<<nblk, 256, 0, stream>>>(agg, w2s + i * 1024, b2s + i * 32, h,
                                             stats + (i + 1) * 64);
    }

    int pthreads = ((NN + PR - 1) / PR) * 32;
    pool_kernel<<<(pthreads + 255) / 256, 256, 0, stream>>>(h, batch, pooled, pcnt);
    head_kernel<<<1, 128, 0, stream>>>(pooled, pcnt, stats + 3 * 64, gs + 2 * 32,
                                       bes + 2 * 32, fc1w, fc1b, fc2w, fc2b, out);
}

// Round 9
// 662.027 us; speedup vs baseline: 1.0701x; 1.0701x over previous
//
#include <hip/hip_runtime.h>
#include <hip/hip_bf16.h>

#define NN   100000
#define EE   3200000
#define HH   32
#define BB   128
#define KMAX 96
#define NBKT 256         // dst buckets
#define NBKT2 512        // dst buckets x src class (lo/hi)
#define BSPAN 391        // ceil(NN/NBKT)
#define WSPAN 98         // csr-build window (4 windows/bucket)
#define EBLK 256         // edge-chunk blocks
#define CHUNK 12500      // EE / EBLK exactly
#define NSPLIT 50000     // src class split: lo = src<NSPLIT (3.2 MB q window)

typedef float nfloat4 __attribute__((ext_vector_type(4)));   // native vec for nontemporal builtins

// ws layout (bytes), non-overlapping (~60 MB)
static constexpr size_t Q_OFF      = 0;           // N*32 bf16 = 6.4 MB
static constexpr size_t AGG_OFF    = 6400000;     // N*32 f32 = 12.8 MB
static constexpr size_t H_OFF      = 19200000;    // N*32 f32 = 12.8 MB
static constexpr size_t EPACK_OFF  = 32000000;    // EE int = 12.8 MB
static constexpr size_t SRC_OFF    = 44800000;    // EE int (lo dense, then hi dense)
static constexpr size_t OFFLO_OFF  = 57600000;    // (N+1) int
static constexpr size_t OFFHI_OFF  = 58100000;    // (N+1) int
static constexpr size_t HIST_OFF   = 58600000;    // EBLK*NBKT2 int = 512 KB
static constexpr size_t START_OFF  = 59200000;    // EBLK*NBKT2 int = 512 KB
static constexpr size_t KBASE_OFF  = 59800000;    // (NBKT2+1) int
static constexpr size_t STATS_OFF  = 59810000;    // 4 layers x 64 f32
static constexpr size_t POOLED_OFF = 59811024;    // B*32 f32
static constexpr size_t PCNT_OFF   = 59827408;    // B f32
static constexpr size_t ZERO_OFF   = STATS_OFF;
static constexpr size_t ZERO_BYTES = 17920;

// ---- K1: per-block LDS histogram over (dst bucket, src class)
__global__ __launch_bounds__(256) void hist_kernel(const int* __restrict__ ei,
                                                   int* __restrict__ hist) {
    __shared__ int lh[NBKT2];
    int tid = threadIdx.x, blk = blockIdx.x;
    for (int i = tid; i < NBKT2; i += 256) lh[i] = 0;
    __syncthreads();
    int e0 = blk * CHUNK;
    for (int e = e0 + tid; e < e0 + CHUNK; e += 256) {
        int s = ei[e];
        int d = ei[EE + e];
        int key = d / BSPAN + (s >= NSPLIT ? NBKT : 0);
        atomicAdd(&lh[key], 1);
    }
    __syncthreads();
    for (int i = tid; i < NBKT2; i += 256) hist[blk * NBKT2 + i] = lh[i];
}

// ---- K2 (fused totals+scan+starts): 1 block, thread t owns virtual bucket t
__global__ __launch_bounds__(NBKT2) void bucket_scan_kernel(const int* __restrict__ hist,
                                                            int* __restrict__ kbase,
                                                            int* __restrict__ start) {
    __shared__ int sm[NBKT2];
    int t = threadIdx.x;
    int mine = 0;
    for (int blk = 0; blk < EBLK; blk++) mine += hist[blk * NBKT2 + t];
    sm[t] = mine;
    __syncthreads();
    for (int off = 1; off < NBKT2; off <<= 1) {
        int v = (t >= off) ? sm[t - off] : 0;
        __syncthreads();
        sm[t] += v;
        __syncthreads();
    }
    int base = sm[t] - mine;   // exclusive
    kbase[t] = base;
    if (t == NBKT2 - 1) kbase[NBKT2] = sm[t];
    int run = base;
    for (int blk = 0; blk < EBLK; blk++) {
        start[blk * NBKT2 + t] = run;
        run += hist[blk * NBKT2 + t];
    }
}

// ---- K3: scatter packed (src | dstoff<<17) grouped by (class, bucket)
__global__ __launch_bounds__(256) void scatter_kernel(const int* __restrict__ ei,
                                                      const int* __restrict__ start,
                                                      int* __restrict__ epack) {
    __shared__ int loff[NBKT2];
    int tid = threadIdx.x, blk = blockIdx.x;
    for (int i = tid; i < NBKT2; i += 256) loff[i] = start[blk * NBKT2 + i];
    __syncthreads();
    int e0 = blk * CHUNK;
    for (int e = e0 + tid; e < e0 + CHUNK; e += 256) {
        int s = ei[e];
        int d = ei[EE + e];
        int b = d / BSPAN;
        int key = b + (s >= NSPLIT ? NBKT : 0);
        int slot = atomicAdd(&loff[key], 1);
        epack[slot] = s | ((d - b * BSPAN) << 17);
    }
}

// ---- K4: compact CSR build (proven r6 form), run per class x bucket x window.
// 2048 blocks: cls = blk>>10. Writes class-local dense srcs + exact off arrays.
__global__ __launch_bounds__(256) void csr_compact_kernel(const int* __restrict__ epack,
                                                          const int* __restrict__ kbase,
                                                          int* __restrict__ off_lo,
                                                          int* __restrict__ off_hi,
                                                          int* __restrict__ srcs) {
    __shared__ int lcnt[WSPAN];
    __shared__ int lbase[WSPAN + 1];
    __shared__ int lcsr[WSPAN * KMAX];   // 37632 B
    __shared__ int sh_before;
    int blk = blockIdx.x;
    int cls = blk >> 10;
    int bw = blk & 1023;
    int b = bw >> 2, w = bw & 3;
    int* off = cls ? off_hi : off_lo;
    int base = b * BSPAN;
    int span = NN - base;
    if (span <= 0) return;
    if (span > BSPAN) span = BSPAN;
    int wstart = w * WSPAN;
    if (wstart >= span) return;
    int wend = min(wstart + WSPAN, span);
    int wn = wend - wstart;
    int tid = threadIdx.x;
    if (tid == 0) sh_before = 0;
    for (int i = tid; i < wn; i += 256) lcnt[i] = 0;
    __syncthreads();
    int p0 = kbase[cls * NBKT + b], p1 = kbase[cls * NBKT + b + 1];
    int nbefore = 0;
    for (int i = p0 + tid; i < p1; i += 256) {
        int wd = epack[i];
        int ld = wd >> 17;
        if (ld < wstart) nbefore++;
        else if (ld < wend) {
            int slot = atomicAdd(&lcnt[ld - wstart], 1);
            if (slot < KMAX) lcsr[(ld - wstart) * KMAX + slot] = wd & 0x1FFFF;
        }
    }
    atomicAdd(&sh_before, nbefore);
    __syncthreads();
    if (tid == 0) {
        int run = 0;
        for (int i = 0; i < wn; i++) { lbase[i] = run; run += min(lcnt[i], KMAX); }
        lbase[wn] = run;
    }
    __syncthreads();
    int w0 = p0 + sh_before;
    for (int i = tid; i < wn; i += 256) off[base + wstart + i] = w0 + lbase[i];
    if (base + wend == NN && tid == 0) off[NN] = w0 + lbase[wn];
    int m = lbase[wn];
    for (int j = tid; j < m; j += 256) {
        int lo = 0, hi = wn - 1;
        while (lo < hi) {
            int mid = (lo + hi + 1) >> 1;
            if (lbase[mid] <= j) lo = mid; else hi = mid - 1;
        }
        srcs[w0 + j] = lcsr[lo * KMAX + (j - lbase[lo])];
    }
}

__device__ __forceinline__ unsigned bf16rn(float f) {
    unsigned b = __float_as_uint(f);
    return (b + 0x7fffu + ((b >> 16) & 1u)) >> 16;   // RNE
}

__device__ __forceinline__ void acc_row(float* a, uint4 v) {
    a[0] += __uint_as_float(v.x << 16);
    a[1] += __uint_as_float(v.x & 0xffff0000u);
    a[2] += __uint_as_float(v.y << 16);
    a[3] += __uint_as_float(v.y & 0xffff0000u);
    a[4] += __uint_as_float(v.z << 16);
    a[5] += __uint_as_float(v.z & 0xffff0000u);
    a[6] += __uint_as_float(v.w << 16);
    a[7] += __uint_as_float(v.w & 0xffff0000u);
}

// ---- projection q(bf16, 64 B rows) = BN(h) @ w1; BN from prev raw stats (FIN==32).
template <int FIN>
__global__ __launch_bounds__(256) void proj_kernel(const float* __restrict__ hin,
                                                   const float* __restrict__ w1,
                                                   const float* __restrict__ stats_prev,
                                                   const float* __restrict__ gamma,
                                                   const float* __restrict__ beta,
                                                   uint4* __restrict__ q4) {
    __shared__ float sa[32], sc[32];
    int tid = threadIdx.x;
    if constexpr (FIN == 32) {
        if (tid < 32) {
            float mean = stats_prev[tid] * (1.0f / NN);
            float var  = fmaxf(stats_prev[32 + tid] * (1.0f / NN) - mean * mean, 0.f);
            float av = gamma[tid] * rsqrtf(var + 1e-5f);
            sa[tid] = av;
            sc[tid] = beta[tid] - mean * av;
        }
        __syncthreads();
    }
    int n = blockIdx.x * 256 + tid;
    if (n >= NN) return;
    float acc[32];
#pragma unroll
    for (int c = 0; c < 32; c++) acc[c] = 0.f;
    const float4* h4 = (const float4*)(hin + (size_t)n * FIN);
    for (int jj = 0; jj < FIN; jj += 32) {
        float hv[32];
#pragma unroll
        for (int k = 0; k < 8; k++) {
            float4 v = h4[jj / 4 + k];
            hv[4 * k] = v.x; hv[4 * k + 1] = v.y; hv[4 * k + 2] = v.z; hv[4 * k + 3] = v.w;
        }
        if constexpr (FIN == 32) {
#pragma unroll
            for (int j = 0; j < 32; j++) hv[j] = fmaf(hv[j], sa[j], sc[j]);
        }
#pragma unroll 4
        for (int j = 0; j < 32; j++) {
            float hvj = hv[j];
            const float* wrow = w1 + (size_t)(jj + j) * 32;
#pragma unroll
            for (int c = 0; c < 32; c++) acc[c] = fmaf(hvj, wrow[c], acc[c]);
        }
    }
#pragma unroll
    for (int k = 0; k < 4; k++) {
        uint4 u;
        u.x = bf16rn(acc[8*k+0]) | (bf16rn(acc[8*k+1]) << 16);
        u.y = bf16rn(acc[8*k+2]) | (bf16rn(acc[8*k+3]) << 16);
        u.z = bf16rn(acc[8*k+4]) | (bf16rn(acc[8*k+5]) << 16);
        u.w = bf16rn(acc[8*k+6]) | (bf16rn(acc[8*k+7]) << 16);
        q4[(size_t)n * 4 + k] = u;
    }
}

// ---- gather pass A: agg[n] = q[n] + b1 + sum q[src in lo class] (hot 3.2 MB).
// nt srcs loads + nt agg stores protect the q window in L2.
__global__ __launch_bounds__(256) void gatherA_kernel(const uint4* __restrict__ q4,
                                                      const int* __restrict__ srcs,
                                                      const int* __restrict__ off,
                                                      const float* __restrict__ b1,
                                                      float* __restrict__ agg) {
    int t = blockIdx.x * 256 + threadIdx.x;
    int n = t >> 2;
    if (n >= NN) return;
    int p = t & 3;
    float a[8];
#pragma unroll
    for (int k = 0; k < 8; k++) a[k] = b1[p * 8 + k];
    acc_row(a, q4[(size_t)n * 4 + p]);   // self term
    int o0 = off[n];
    int d = off[n + 1] - o0;
    const int* lst = srcs + o0;
    int i = 0;
    for (; i + 8 <= d; i += 8) {
        int s0 = __builtin_nontemporal_load(lst + i);
        int s1 = __builtin_nontemporal_load(lst + i + 1);
        int s2 = __builtin_nontemporal_load(lst + i + 2);
        int s3 = __builtin_nontemporal_load(lst + i + 3);
        int s4 = __builtin_nontemporal_load(lst + i + 4);
        int s5 = __builtin_nontemporal_load(lst + i + 5);
        int s6 = __builtin_nontemporal_load(lst + i + 6);
        int s7 = __builtin_nontemporal_load(lst + i + 7);
        uint4 v0 = q4[(size_t)s0 * 4 + p];
        uint4 v1 = q4[(size_t)s1 * 4 + p];
        uint4 v2 = q4[(size_t)s2 * 4 + p];
        uint4 v3 = q4[(size_t)s3 * 4 + p];
        uint4 v4 = q4[(size_t)s4 * 4 + p];
        uint4 v5 = q4[(size_t)s5 * 4 + p];
        uint4 v6 = q4[(size_t)s6 * 4 + p];
        uint4 v7 = q4[(size_t)s7 * 4 + p];
        acc_row(a, v0); acc_row(a, v1); acc_row(a, v2); acc_row(a, v3);
        acc_row(a, v4); acc_row(a, v5); acc_row(a, v6); acc_row(a, v7);
    }
    for (; i < d; i++) {
        int s = __builtin_nontemporal_load(lst + i);
        acc_row(a, q4[(size_t)s * 4 + p]);
    }
    nfloat4* ar = (nfloat4*)(agg + (size_t)n * 32 + p * 8);
    nfloat4 f0, f1;
    f0.x = a[0]; f0.y = a[1]; f0.z = a[2]; f0.w = a[3];
    f1.x = a[4]; f1.y = a[5]; f1.z = a[6]; f1.w = a[7];
    __builtin_nontemporal_store(f0, ar);
    __builtin_nontemporal_store(f1, ar + 1);
}

// ---- gather pass B: agg[n] += sum q[src in hi class] (hot = upper 3.2 MB).
__global__ __launch_bounds__(256) void gatherB_kernel(const uint4* __restrict__ q4,
                                                      const int* __restrict__ srcs,
                                                      const int* __restrict__ off,
                                                      float* __restrict__ agg) {
    int t = blockIdx.x * 256 + threadIdx.x;
    int n = t >> 2;
    if (n >= NN) return;
    int p = t & 3;
    float a[8];
#pragma unroll
    for (int k = 0; k < 8; k++) a[k] = 0.f;
    int o0 = off[n];
    int d = off[n + 1] - o0;
    const int* lst = srcs + o0;
    int i = 0;
    for (; i + 8 <= d; i += 8) {
        int s0 = __builtin_nontemporal_load(lst + i);
        int s1 = __builtin_nontemporal_load(lst + i + 1);
        int s2 = __builtin_nontemporal_load(lst + i + 2);
        int s3 = __builtin_nontemporal_load(lst + i + 3);
        int s4 = __builtin_nontemporal_load(lst + i + 4);
        int s5 = __builtin_nontemporal_load(lst + i + 5);
        int s6 = __builtin_nontemporal_load(lst + i + 6);
        int s7 = __builtin_nontemporal_load(lst + i + 7);
        uint4 v0 = q4[(size_t)s0 * 4 + p];
        uint4 v1 = q4[(size_t)s1 * 4 + p];
        uint4 v2 = q4[(size_t)s2 * 4 + p];
        uint4 v3 = q4[(size_t)s3 * 4 + p];
        uint4 v4 = q4[(size_t)s4 * 4 + p];
        uint4 v5 = q4[(size_t)s5 * 4 + p];
        uint4 v6 = q4[(size_t)s6 * 4 + p];
        uint4 v7 = q4[(size_t)s7 * 4 + p];
        acc_row(a, v0); acc_row(a, v1); acc_row(a, v2); acc_row(a, v3);
        acc_row(a, v4); acc_row(a, v5); acc_row(a, v6); acc_row(a, v7);
    }
    for (; i < d; i++) {
        int s = __builtin_nontemporal_load(lst + i);
        acc_row(a, q4[(size_t)s * 4 + p]);
    }
    nfloat4* ar = (nfloat4*)(agg + (size_t)n * 32 + p * 8);
    nfloat4 g0 = __builtin_nontemporal_load(ar);
    nfloat4 g1 = __builtin_nontemporal_load(ar + 1);
    g0.x += a[0]; g0.y += a[1]; g0.z += a[2]; g0.w += a[3];
    g1.x += a[4]; g1.y += a[5]; g1.z += a[6]; g1.w += a[7];
    __builtin_nontemporal_store(g0, ar);
    __builtin_nontemporal_store(g1, ar + 1);
}

// ---- MLP tail: h = relu(relu(agg)@w2 + b2); accumulate raw BN stats (layer slot).
__global__ __launch_bounds__(256) void mlp_kernel(const float* __restrict__ agg,
                                                  const float* __restrict__ w2,
                                                  const float* __restrict__ b2,
                                                  float* __restrict__ r,
                                                  float* __restrict__ stats) {
    __shared__ float tile[256 * 33];
    __shared__ float ps[8 * 32];
    __shared__ float pq[8 * 32];
    int tid = threadIdx.x;
    int n = blockIdx.x * 256 + tid;
    float rc[32];
    if (n < NN) {
        float u[32];
        const float4* a4 = (const float4*)(agg + (size_t)n * 32);
#pragma unroll
        for (int k = 0; k < 8; k++) {
            float4 v = a4[k];
            u[4*k]   = fmaxf(v.x, 0.f);
            u[4*k+1] = fmaxf(v.y, 0.f);
            u[4*k+2] = fmaxf(v.z, 0.f);
            u[4*k+3] = fmaxf(v.w, 0.f);
        }
#pragma unroll
        for (int c = 0; c < 32; c++) rc[c] = b2[c];
#pragma unroll 4
        for (int j = 0; j < 32; j++) {
            float uj = u[j];
            const float* wrow = w2 + (size_t)j * 32;
#pragma unroll
            for (int c = 0; c < 32; c++) rc[c] = fmaf(uj, wrow[c], rc[c]);
        }
#pragma unroll
        for (int c = 0; c < 32; c++) rc[c] = fmaxf(rc[c], 0.f);
        float4* rr = (float4*)(r + (size_t)n * 32);
#pragma unroll
        for (int k = 0; k < 8; k++) {
            float4 v; v.x = rc[4*k]; v.y = rc[4*k+1]; v.z = rc[4*k+2]; v.w = rc[4*k+3];
            rr[k] = v;
        }
    } else {
#pragma unroll
        for (int c = 0; c < 32; c++) rc[c] = 0.f;
    }
#pragma unroll
    for (int c = 0; c < 32; c++) tile[tid * 33 + c] = rc[c];
    __syncthreads();
    {
        int c = tid & 31, rb = tid >> 5;
        float s = 0.f, sq = 0.f;
        for (int it = 0; it < 32; it++) {
            float v = tile[(rb * 32 + it) * 33 + c];
            s += v; sq += v * v;
        }
        ps[rb * 32 + c] = s; pq[rb * 32 + c] = sq;
    }
    __syncthreads();
    if (tid < 32) {
        float s = 0.f, sq = 0.f;
#pragma unroll
        for (int rb = 0; rb < 8; rb++) { s += ps[rb * 32 + tid]; sq += pq[rb * 32 + tid]; }
        atomicAdd(&stats[tid], s);
        atomicAdd(&stats[32 + tid], sq);
    }
}

// ---- pooling: segment sums of raw h3 (sorted batch -> run-length flush)
#define PR 16
__global__ __launch_bounds__(256) void pool_kernel(const float* __restrict__ h,
                                                   const int* __restrict__ batch,
                                                   float* __restrict__ pooled,
                                                   float* __restrict__ pcnt) {
    int t = blockIdx.x * 256 + threadIdx.x;
    int c = t & 31;
    int g = t >> 5;
    int r0 = g * PR;
    if (r0 >= NN) return;
    int r1 = min(r0 + PR, NN);
    int cur = batch[r0];
    float acc = 0.f, cn = 0.f;
    for (int rr = r0; rr < r1; rr++) {
        int b = batch[rr];
        if (b != cur) {
            atomicAdd(&pooled[cur * 32 + c], acc);
            if (c == 0) atomicAdd(&pcnt[cur], cn);
            acc = 0.f; cn = 0.f; cur = b;
        }
        acc += h[(size_t)rr * 32 + c];
        cn += 1.f;
    }
    atomicAdd(&pooled[cur * 32 + c], acc);
    if (c == 0) atomicAdd(&pcnt[cur], cn);
}

// ---- head: BN3 (from raw stats3) on pooled means, fc1+relu, fc2, log_softmax
__global__ __launch_bounds__(128) void head_kernel(const float* __restrict__ pooled,
                                                   const float* __restrict__ pcnt,
                                                   const float* __restrict__ stats3,
                                                   const float* __restrict__ g3,
                                                   const float* __restrict__ be3,
                                                   const float* __restrict__ fc1w,
                                                   const float* __restrict__ fc1b,
                                                   const float* __restrict__ fc2w,
                                                   const float* __restrict__ fc2b,
                                                   float* __restrict__ out) {
    __shared__ float sa[32], sc[32];
    int g = threadIdx.x;
    if (g < 32) {
        float mean = stats3[g] * (1.0f / NN);
        float var  = fmaxf(stats3[32 + g] * (1.0f / NN) - mean * mean, 0.f);
        float av = g3[g] * rsqrtf(var + 1e-5f);
        sa[g] = av;
        sc[g] = be3[g] - mean * av;
    }
    __syncthreads();
    if (g >= BB) return;
    float inv = 1.f / fmaxf(pcnt[g], 1.f);
    float xv[32];
#pragma unroll
    for (int c = 0; c < 32; c++) xv[c] = fmaf(sa[c], pooled[g * 32 + c] * inv, sc[c]);
    float u[32];
#pragma unroll 4
    for (int k = 0; k < 32; k++) {
        float s = fc1b[k];
#pragma unroll
        for (int c = 0; c < 32; c++) s = fmaf(xv[c], fc1w[c * 32 + k], s);
        u[k] = fmaxf(s, 0.f);
    }
    float l[8];
#pragma unroll
    for (int o = 0; o < 8; o++) {
        float s = fc2b[o];
#pragma unroll
        for (int k = 0; k < 32; k++) s = fmaf(u[k], fc2w[k * 8 + o], s);
        l[o] = s;
    }
    float m = l[0];
#pragma unroll
    for (int o = 1; o < 8; o++) m = fmaxf(m, l[o]);
    float se = 0.f;
#pragma unroll
    for (int o = 0; o < 8; o++) se += expf(l[o] - m);
    float lse = logf(se) + m;
#pragma unroll
    for (int o = 0; o < 8; o++) out[g * 8 + o] = l[o] - lse;
}

extern "C" void kernel_launch(void* const* d_in, const int* in_sizes, int n_in,
                              void* d_out, int out_size, void* d_ws, size_t ws_size,
                              hipStream_t stream) {
    const float* x    = (const float*)d_in[0];
    const int*   ei   = (const int*)d_in[1];
    const int*   batch= (const int*)d_in[2];
    const float* w1_0 = (const float*)d_in[3];
    const float* b1_0 = (const float*)d_in[4];
    const float* w2_0 = (const float*)d_in[5];
    const float* b2_0 = (const float*)d_in[6];
    const float* g_0  = (const float*)d_in[7];
    const float* be_0 = (const float*)d_in[8];
    const float* w1s  = (const float*)d_in[9];
    const float* b1s  = (const float*)d_in[10];
    const float* w2s  = (const float*)d_in[11];
    const float* b2s  = (const float*)d_in[12];
    const float* gs   = (const float*)d_in[13];
    const float* bes  = (const float*)d_in[14];
    const float* fc1w = (const float*)d_in[15];
    const float* fc1b = (const float*)d_in[16];
    const float* fc2w = (const float*)d_in[17];
    const float* fc2b = (const float*)d_in[18];
    float* out = (float*)d_out;

    char* ws = (char*)d_ws;
    uint4*    q4     = (uint4*)(ws + Q_OFF);
    float*    agg    = (float*)(ws + AGG_OFF);
    float*    h      = (float*)(ws + H_OFF);
    int*      epack  = (int*)(ws + EPACK_OFF);
    int*      srcs   = (int*)(ws + SRC_OFF);
    int*      off_lo = (int*)(ws + OFFLO_OFF);
    int*      off_hi = (int*)(ws + OFFHI_OFF);
    int*      hist   = (int*)(ws + HIST_OFF);
    int*      start  = (int*)(ws + START_OFF);
    int*      kbase  = (int*)(ws + KBASE_OFF);
    float*    stats  = (float*)(ws + STATS_OFF);   // 4 slots x 64
    float*    pooled = (float*)(ws + POOLED_OFF);
    float*    pcnt   = (float*)(ws + PCNT_OFF);

    (void)hipMemsetAsync(ws + ZERO_OFF, 0, ZERO_BYTES, stream);

    // CSR build chain (class-split dense)
    hist_kernel<<<EBLK, 256, 0, stream>>>(ei, hist);
    bucket_scan_kernel<<<1, NBKT2, 0, stream>>>(hist, kbase, start);
    scatter_kernel<<<EBLK, 256, 0, stream>>>(ei, start, epack);
    csr_compact_kernel<<<2048, 256, 0, stream>>>(epack, kbase, off_lo, off_hi, srcs);

    const int nblk = (NN + 255) / 256;
    const int gblk = (NN * 4 + 255) / 256;

    // layer 0 (F_IN=128, no input BN)
    proj_kernel<128><<<nblk, 256, 0, stream>>>(x, w1_0, nullptr, nullptr, nullptr, q4);
    gatherA_kernel<<<gblk, 256, 0, stream>>>(q4, srcs, off_lo, b1_0, agg);
    gatherB_kernel<<<gblk, 256, 0, stream>>>(q4, srcs, off_hi, agg);
    mlp_kernel<<<nblk, 256, 0, stream>>>(agg, w2_0, b2_0, h, stats);

    // layers 1..3, prev BN computed in proj from raw stats slot
    for (int i = 0; i < 3; i++) {
        const float* st_prev = stats + i * 64;
        proj_kernel<32><<<nblk, 256, 0, stream>>>(h, w1s + i * 1024, st_prev,
                                                  gs + i * 32, bes + i * 32, q4);
        gatherA_kernel<<<gblk, 256, 0, stream>>>(q4, srcs, off_lo, b1s + i * 32, agg);
        gatherB_kernel<<<gblk, 256, 0, stream>>>(q4, srcs, off_hi, agg);
        mlp_kernel<<<nblk, 256, 0, stream>>>(agg, w2s + i * 1024, b2s + i * 32, h,
                                             stats + (i + 1) * 64);
    }

    int pthreads = ((NN + PR - 1) / PR) * 32;
    pool_kernel<<<(pthreads + 255) / 256, 256, 0, stream>>>(h, batch, pooled, pcnt);
    head_kernel<<<1, 128, 0, stream>>>(pooled, pcnt, stats + 3 * 64, gs + 2 * 32,
                                       bes + 2 * 32, fc1w, fc1b, fc2w, fc2b, out);
}

// Round 10
// 592.059 us; speedup vs baseline: 1.1966x; 1.1182x over previous
//
#include <hip/hip_runtime.h>
#include <hip/hip_bf16.h>

#define NN   100000
#define EE   3200000
#define HH   32
#define BB   128
#define KMAX 96
#define LSTRIDE 97       // LDS row stride (96 is 0 mod 32 -> bank storm)
#define NBKT 256         // dst buckets
#define BSPAN 391        // ceil(NN/NBKT)
#define WSPAN 98         // csr-build window (4 windows/bucket)
#define EBLK 256         // edge-chunk blocks
#define CHUNK 12500      // EE / EBLK exactly

// ws layout (bytes), non-overlapping (~60 MB)
static constexpr size_t Q_OFF      = 0;           // N*32 bf16 = 6.4 MB
static constexpr size_t AGG_OFF    = 6400000;     // N*32 f32 = 12.8 MB
static constexpr size_t H_OFF      = 19200000;    // N*32 f32 = 12.8 MB
static constexpr size_t EPACK_OFF  = 32000000;    // EE int = 12.8 MB
static constexpr size_t SRC_OFF    = 44800000;    // EE int dense csr
static constexpr size_t OFF_OFF    = 57600000;    // (N+1) int
static constexpr size_t HIST_OFF   = 58100000;    // EBLK*NBKT int = 256 KB
static constexpr size_t START_OFF  = 58400000;    // EBLK*NBKT int = 256 KB
static constexpr size_t BBASE_OFF  = 58700000;    // (NBKT+1) int
static constexpr size_t STATS_OFF  = 58710000;    // 4 layers x 64 f32
static constexpr size_t POOLED_OFF = 58711024;    // B*32 f32
static constexpr size_t PCNT_OFF   = 58727408;    // B f32
static constexpr size_t ZERO_OFF   = STATS_OFF;
static constexpr size_t ZERO_BYTES = 17920;

// ---- K1: per-block LDS histogram of dst buckets
__global__ __launch_bounds__(256) void hist_kernel(const int* __restrict__ ei,
                                                   int* __restrict__ hist) {
    __shared__ int lh[NBKT];
    int tid = threadIdx.x, blk = blockIdx.x;
    for (int i = tid; i < NBKT; i += 256) lh[i] = 0;
    __syncthreads();
    int e0 = blk * CHUNK;
    for (int e = e0 + tid; e < e0 + CHUNK; e += 256) {
        int d = ei[EE + e];
        atomicAdd(&lh[d / BSPAN], 1);
    }
    __syncthreads();
    for (int i = tid; i < NBKT; i += 256) hist[blk * NBKT + i] = lh[i];
}

// ---- K2 (fused totals+scan+starts): 1 block, thread t owns bucket t
__global__ __launch_bounds__(NBKT) void bucket_scan_kernel(const int* __restrict__ hist,
                                                           int* __restrict__ bbase,
                                                           int* __restrict__ start) {
    __shared__ int sm[NBKT];
    int t = threadIdx.x;
    int mine = 0;
    for (int blk = 0; blk < EBLK; blk++) mine += hist[blk * NBKT + t];
    sm[t] = mine;
    __syncthreads();
    for (int off = 1; off < NBKT; off <<= 1) {
        int v = (t >= off) ? sm[t - off] : 0;
        __syncthreads();
        sm[t] += v;
        __syncthreads();
    }
    int base = sm[t] - mine;   // exclusive
    bbase[t] = base;
    if (t == NBKT - 1) bbase[NBKT] = sm[t];
    int run = base;
    for (int blk = 0; blk < EBLK; blk++) {
        start[blk * NBKT + t] = run;
        run += hist[blk * NBKT + t];
    }
}

// ---- K3: scatter packed (src | dstoff<<17) into bucket-grouped array
__global__ __launch_bounds__(256) void scatter_kernel(const int* __restrict__ ei,
                                                      const int* __restrict__ start,
                                                      int* __restrict__ epack) {
    __shared__ int loff[NBKT];
    int tid = threadIdx.x, blk = blockIdx.x;
    for (int i = tid; i < NBKT; i += 256) loff[i] = start[blk * NBKT + i];
    __syncthreads();
    int e0 = blk * CHUNK;
    for (int e = e0 + tid; e < e0 + CHUNK; e += 256) {
        int s = ei[e];
        int d = ei[EE + e];
        int b = d / BSPAN;
        int slot = atomicAdd(&loff[b], 1);
        epack[slot] = s | ((d - b * BSPAN) << 17);
    }
}

// ---- K4: compact CSR build (r6 form + stride-97 LDS to kill bank conflicts)
__global__ __launch_bounds__(256) void csr_compact_kernel(const int* __restrict__ epack,
                                                          const int* __restrict__ bbase,
                                                          int* __restrict__ off,
                                                          int* __restrict__ srcs) {
    __shared__ int lcnt[WSPAN];
    __shared__ int lbase[WSPAN + 1];
    __shared__ int lcsr[WSPAN * LSTRIDE];   // 98*97*4 = 38024 B
    __shared__ int sh_before;
    int blk = blockIdx.x;
    int b = blk >> 2, w = blk & 3;
    int base = b * BSPAN;
    int span = NN - base;
    if (span <= 0) return;
    if (span > BSPAN) span = BSPAN;
    int wstart = w * WSPAN;
    if (wstart >= span) return;
    int wend = min(wstart + WSPAN, span);
    int wn = wend - wstart;
    int tid = threadIdx.x;
    if (tid == 0) sh_before = 0;
    for (int i = tid; i < wn; i += 256) lcnt[i] = 0;
    __syncthreads();
    int p0 = bbase[b], p1 = bbase[b + 1];
    int nbefore = 0;
    for (int i = p0 + tid; i < p1; i += 256) {
        int wd = epack[i];
        int ld = wd >> 17;
        if (ld < wstart) nbefore++;
        else if (ld < wend) {
            int slot = atomicAdd(&lcnt[ld - wstart], 1);
            if (slot < KMAX) lcsr[(ld - wstart) * LSTRIDE + slot] = wd & 0x1FFFF;
        }
    }
    atomicAdd(&sh_before, nbefore);
    __syncthreads();
    if (tid == 0) {
        int run = 0;
        for (int i = 0; i < wn; i++) { lbase[i] = run; run += min(lcnt[i], KMAX); }
        lbase[wn] = run;
    }
    __syncthreads();
    int w0 = p0 + sh_before;
    for (int i = tid; i < wn; i += 256) off[base + wstart + i] = w0 + lbase[i];
    if (base + wend == NN && tid == 0) off[NN] = w0 + lbase[wn];
    int m = lbase[wn];
    for (int j = tid; j < m; j += 256) {
        int lo = 0, hi = wn - 1;
        while (lo < hi) {
            int mid = (lo + hi + 1) >> 1;
            if (lbase[mid] <= j) lo = mid; else hi = mid - 1;
        }
        srcs[w0 + j] = lcsr[lo * LSTRIDE + (j - lbase[lo])];
    }
}

__device__ __forceinline__ unsigned bf16rn(float f) {
    unsigned b = __float_as_uint(f);
    return (b + 0x7fffu + ((b >> 16) & 1u)) >> 16;   // RNE
}

__device__ __forceinline__ void acc_row(float* a, uint4 v) {
    a[0] += __uint_as_float(v.x << 16);
    a[1] += __uint_as_float(v.x & 0xffff0000u);
    a[2] += __uint_as_float(v.y << 16);
    a[3] += __uint_as_float(v.y & 0xffff0000u);
    a[4] += __uint_as_float(v.z << 16);
    a[5] += __uint_as_float(v.z & 0xffff0000u);
    a[6] += __uint_as_float(v.w << 16);
    a[7] += __uint_as_float(v.w & 0xffff0000u);
}

// ---- projection q(bf16) = BN(h) @ w1, 4-way K-split: wave wv of each block owns
// K-rows [wv*FIN/4, (wv+1)*FIN/4) for the block's 64 nodes (w1 rows stay
// wave-uniform -> scalar loads); partials reduced via padded LDS. Grid = N/64.
template <int FIN>
__global__ __launch_bounds__(256) void proj_kernel(const float* __restrict__ hin,
                                                   const float* __restrict__ w1,
                                                   const float* __restrict__ stats_prev,
                                                   const float* __restrict__ gamma,
                                                   const float* __restrict__ beta,
                                                   uint4* __restrict__ q4) {
    constexpr int JC = FIN / 4;           // K rows per wave: 32 (FIN=128) / 8 (FIN=32)
    __shared__ float sa[32], sc[32];
    __shared__ float part[4 * 64 * 33];   // [wv][node][ch], +1 pad -> 33792 B
    int tid = threadIdx.x;
    if constexpr (FIN == 32) {
        if (tid < 32) {
            float mean = stats_prev[tid] * (1.0f / NN);
            float var  = fmaxf(stats_prev[32 + tid] * (1.0f / NN) - mean * mean, 0.f);
            float av = gamma[tid] * rsqrtf(var + 1e-5f);
            sa[tid] = av;
            sc[tid] = beta[tid] - mean * av;
        }
        __syncthreads();
    }
    int wv = __builtin_amdgcn_readfirstlane(tid >> 6);   // K-part, wave-uniform
    int ln = tid & 63;                                   // node within block
    int n = blockIdx.x * 64 + ln;
    float acc[32];
#pragma unroll
    for (int c = 0; c < 32; c++) acc[c] = 0.f;
    if (n < NN) {
        const float4* h4 = (const float4*)(hin + (size_t)n * FIN + wv * JC);
        float hv[JC];
#pragma unroll
        for (int k = 0; k < JC / 4; k++) {
            float4 v = h4[k];
            hv[4*k] = v.x; hv[4*k+1] = v.y; hv[4*k+2] = v.z; hv[4*k+3] = v.w;
        }
        if constexpr (FIN == 32) {
#pragma unroll
            for (int j = 0; j < JC; j++) hv[j] = fmaf(hv[j], sa[wv * JC + j], sc[wv * JC + j]);
        }
#pragma unroll 4
        for (int j = 0; j < JC; j++) {
            float hvj = hv[j];
            const float* wrow = w1 + (size_t)(wv * JC + j) * 32;  // wave-uniform -> s_load
#pragma unroll
            for (int c = 0; c < 32; c++) acc[c] = fmaf(hvj, wrow[c], acc[c]);
        }
    }
    float* my = part + (wv * 64 + ln) * 33;
#pragma unroll
    for (int c = 0; c < 32; c++) my[c] = acc[c];
    __syncthreads();
    // reduce 4 partials; thread t -> node t>>2, channels (t&3)*8..+8; write bf16 q
    int node = tid >> 2, p = tid & 3;
    int n2 = blockIdx.x * 64 + node;
    if (n2 >= NN) return;
    float r[8];
#pragma unroll
    for (int k = 0; k < 8; k++) {
        int c = p * 8 + k;
        r[k] = (part[(0 * 64 + node) * 33 + c] + part[(1 * 64 + node) * 33 + c])
             + (part[(2 * 64 + node) * 33 + c] + part[(3 * 64 + node) * 33 + c]);
    }
    uint4 u;
    u.x = bf16rn(r[0]) | (bf16rn(r[1]) << 16);
    u.y = bf16rn(r[2]) | (bf16rn(r[3]) << 16);
    u.z = bf16rn(r[4]) | (bf16rn(r[5]) << 16);
    u.w = bf16rn(r[6]) | (bf16rn(r[7]) << 16);
    q4[(size_t)n2 * 4 + p] = u;
}

// ---- gather: agg[n] = q[n] + b1 + sum q[src]. 4 lanes/node x 16 B, 8-unrolled.
__global__ __launch_bounds__(256) void gather_kernel(const uint4* __restrict__ q4,
                                                     const int* __restrict__ srcs,
                                                     const int* __restrict__ off,
                                                     const float* __restrict__ b1,
                                                     float* __restrict__ agg) {
    int t = blockIdx.x * 256 + threadIdx.x;
    int n = t >> 2;
    if (n >= NN) return;
    int p = t & 3;
    float a[8];
#pragma unroll
    for (int k = 0; k < 8; k++) a[k] = b1[p * 8 + k];
    acc_row(a, q4[(size_t)n * 4 + p]);   // self term
    int o0 = off[n];
    int d = off[n + 1] - o0;
    const int* lst = srcs + o0;
    int i = 0;
    for (; i + 8 <= d; i += 8) {
        int s0 = __builtin_nontemporal_load(lst + i);
        int s1 = __builtin_nontemporal_load(lst + i + 1);
        int s2 = __builtin_nontemporal_load(lst + i + 2);
        int s3 = __builtin_nontemporal_load(lst + i + 3);
        int s4 = __builtin_nontemporal_load(lst + i + 4);
        int s5 = __builtin_nontemporal_load(lst + i + 5);
        int s6 = __builtin_nontemporal_load(lst + i + 6);
        int s7 = __builtin_nontemporal_load(lst + i + 7);
        uint4 v0 = q4[(size_t)s0 * 4 + p];
        uint4 v1 = q4[(size_t)s1 * 4 + p];
        uint4 v2 = q4[(size_t)s2 * 4 + p];
        uint4 v3 = q4[(size_t)s3 * 4 + p];
        uint4 v4 = q4[(size_t)s4 * 4 + p];
        uint4 v5 = q4[(size_t)s5 * 4 + p];
        uint4 v6 = q4[(size_t)s6 * 4 + p];
        uint4 v7 = q4[(size_t)s7 * 4 + p];
        acc_row(a, v0); acc_row(a, v1); acc_row(a, v2); acc_row(a, v3);
        acc_row(a, v4); acc_row(a, v5); acc_row(a, v6); acc_row(a, v7);
    }
    for (; i < d; i++) {
        int s = __builtin_nontemporal_load(lst + i);
        acc_row(a, q4[(size_t)s * 4 + p]);
    }
    float4* ar = (float4*)(agg + (size_t)n * 32 + p * 8);
    float4 f0, f1;
    f0.x = a[0]; f0.y = a[1]; f0.z = a[2]; f0.w = a[3];
    f1.x = a[4]; f1.y = a[5]; f1.z = a[6]; f1.w = a[7];
    ar[0] = f0; ar[1] = f1;
}

// ---- MLP tail: h = relu(relu(agg)@w2 + b2); accumulate raw BN stats (layer slot).
__global__ __launch_bounds__(256) void mlp_kernel(const float* __restrict__ agg,
                                                  const float* __restrict__ w2,
                                                  const float* __restrict__ b2,
                                                  float* __restrict__ r,
                                                  float* __restrict__ stats) {
    __shared__ float tile[256 * 33];
    __shared__ float ps[8 * 32];
    __shared__ float pq[8 * 32];
    int tid = threadIdx.x;
    int n = blockIdx.x * 256 + tid;
    float rc[32];
    if (n < NN) {
        float u[32];
        const float4* a4 = (const float4*)(agg + (size_t)n * 32);
#pragma unroll
        for (int k = 0; k < 8; k++) {
            float4 v = a4[k];
            u[4*k]   = fmaxf(v.x, 0.f);
            u[4*k+1] = fmaxf(v.y, 0.f);
            u[4*k+2] = fmaxf(v.z, 0.f);
            u[4*k+3] = fmaxf(v.w, 0.f);
        }
#pragma unroll
        for (int c = 0; c < 32; c++) rc[c] = b2[c];
#pragma unroll 4
        for (int j = 0; j < 32; j++) {
            float uj = u[j];
            const float* wrow = w2 + (size_t)j * 32;
#pragma unroll
            for (int c = 0; c < 32; c++) rc[c] = fmaf(uj, wrow[c], rc[c]);
        }
#pragma unroll
        for (int c = 0; c < 32; c++) rc[c] = fmaxf(rc[c], 0.f);
        float4* rr = (float4*)(r + (size_t)n * 32);
#pragma unroll
        for (int k = 0; k < 8; k++) {
            float4 v; v.x = rc[4*k]; v.y = rc[4*k+1]; v.z = rc[4*k+2]; v.w = rc[4*k+3];
            rr[k] = v;
        }
    } else {
#pragma unroll
        for (int c = 0; c < 32; c++) rc[c] = 0.f;
    }
#pragma unroll
    for (int c = 0; c < 32; c++) tile[tid * 33 + c] = rc[c];
    __syncthreads();
    {
        int c = tid & 31, rb = tid >> 5;
        float s = 0.f, sq = 0.f;
        for (int it = 0; it < 32; it++) {
            float v = tile[(rb * 32 + it) * 33 + c];
            s += v; sq += v * v;
        }
        ps[rb * 32 + c] = s; pq[rb * 32 + c] = sq;
    }
    __syncthreads();
    if (tid < 32) {
        float s = 0.f, sq = 0.f;
#pragma unroll
        for (int rb = 0; rb < 8; rb++) { s += ps[rb * 32 + tid]; sq += pq[rb * 32 + tid]; }
        atomicAdd(&stats[tid], s);
        atomicAdd(&stats[32 + tid], sq);
    }
}

// ---- pooling: segment sums of raw h3 (sorted batch -> run-length flush)
#define PR 16
__global__ __launch_bounds__(256) void pool_kernel(const float* __restrict__ h,
                                                   const int* __restrict__ batch,
                                                   float* __restrict__ pooled,
                                                   float* __restrict__ pcnt) {
    int t = blockIdx.x * 256 + threadIdx.x;
    int c = t & 31;
    int g = t >> 5;
    int r0 = g * PR;
    if (r0 >= NN) return;
    int r1 = min(r0 + PR, NN);
    int cur = batch[r0];
    float acc = 0.f, cn = 0.f;
    for (int rr = r0; rr < r1; rr++) {
        int b = batch[rr];
        if (b != cur) {
            atomicAdd(&pooled[cur * 32 + c], acc);
            if (c == 0) atomicAdd(&pcnt[cur], cn);
            acc = 0.f; cn = 0.f; cur = b;
        }
        acc += h[(size_t)rr * 32 + c];
        cn += 1.f;
    }
    atomicAdd(&pooled[cur * 32 + c], acc);
    if (c == 0) atomicAdd(&pcnt[cur], cn);
}

// ---- head: BN3 (from raw stats3) on pooled means, fc1+relu, fc2, log_softmax
__global__ __launch_bounds__(128) void head_kernel(const float* __restrict__ pooled,
                                                   const float* __restrict__ pcnt,
                                                   const float* __restrict__ stats3,
                                                   const float* __restrict__ g3,
                                                   const float* __restrict__ be3,
                                                   const float* __restrict__ fc1w,
                                                   const float* __restrict__ fc1b,
                                                   const float* __restrict__ fc2w,
                                                   const float* __restrict__ fc2b,
                                                   float* __restrict__ out) {
    __shared__ float sa[32], sc[32];
    int g = threadIdx.x;
    if (g < 32) {
        float mean = stats3[g] * (1.0f / NN);
        float var  = fmaxf(stats3[32 + g] * (1.0f / NN) - mean * mean, 0.f);
        float av = g3[g] * rsqrtf(var + 1e-5f);
        sa[g] = av;
        sc[g] = be3[g] - mean * av;
    }
    __syncthreads();
    if (g >= BB) return;
    float inv = 1.f / fmaxf(pcnt[g], 1.f);
    float xv[32];
#pragma unroll
    for (int c = 0; c < 32; c++) xv[c] = fmaf(sa[c], pooled[g * 32 + c] * inv, sc[c]);
    float u[32];
#pragma unroll 4
    for (int k = 0; k < 32; k++) {
        float s = fc1b[k];
#pragma unroll
        for (int c = 0; c < 32; c++) s = fmaf(xv[c], fc1w[c * 32 + k], s);
        u[k] = fmaxf(s, 0.f);
    }
    float l[8];
#pragma unroll
    for (int o = 0; o < 8; o++) {
        float s = fc2b[o];
#pragma unroll
        for (int k = 0; k < 32; k++) s = fmaf(u[k], fc2w[k * 8 + o], s);
        l[o] = s;
    }
    float m = l[0];
#pragma unroll
    for (int o = 1; o < 8; o++) m = fmaxf(m, l[o]);
    float se = 0.f;
#pragma unroll
    for (int o = 0; o < 8; o++) se += expf(l[o] - m);
    float lse = logf(se) + m;
#pragma unroll
    for (int o = 0; o < 8; o++) out[g * 8 + o] = l[o] - lse;
}

extern "C" void kernel_launch(void* const* d_in, const int* in_sizes, int n_in,
                              void* d_out, int out_size, void* d_ws, size_t ws_size,
                              hipStream_t stream) {
    const float* x    = (const float*)d_in[0];
    const int*   ei   = (const int*)d_in[1];
    const int*   batch= (const int*)d_in[2];
    const float* w1_0 = (const float*)d_in[3];
    const float* b1_0 = (const float*)d_in[4];
    const float* w2_0 = (const float*)d_in[5];
    const float* b2_0 = (const float*)d_in[6];
    const float* g_0  = (const float*)d_in[7];
    const float* be_0 = (const float*)d_in[8];
    const float* w1s  = (const float*)d_in[9];
    const float* b1s  = (const float*)d_in[10];
    const float* w2s  = (const float*)d_in[11];
    const float* b2s  = (const float*)d_in[12];
    const float* gs   = (const float*)d_in[13];
    const float* bes  = (const float*)d_in[14];
    const float* fc1w = (const float*)d_in[15];
    const float* fc1b = (const float*)d_in[16];
    const float* fc2w = (const float*)d_in[17];
    const float* fc2b = (const float*)d_in[18];
    float* out = (float*)d_out;

    char* ws = (char*)d_ws;
    uint4*    q4     = (uint4*)(ws + Q_OFF);
    float*    agg    = (float*)(ws + AGG_OFF);
    float*    h      = (float*)(ws + H_OFF);
    int*      epack  = (int*)(ws + EPACK_OFF);
    int*      srcs   = (int*)(ws + SRC_OFF);
    int*      off    = (int*)(ws + OFF_OFF);
    int*      hist   = (int*)(ws + HIST_OFF);
    int*      start  = (int*)(ws + START_OFF);
    int*      bbase  = (int*)(ws + BBASE_OFF);
    float*    stats  = (float*)(ws + STATS_OFF);   // 4 slots x 64
    float*    pooled = (float*)(ws + POOLED_OFF);
    float*    pcnt   = (float*)(ws + PCNT_OFF);

    (void)hipMemsetAsync(ws + ZERO_OFF, 0, ZERO_BYTES, stream);

    // CSR build chain
    hist_kernel<<<EBLK, 256, 0, stream>>>(ei, hist);
    bucket_scan_kernel<<<1, NBKT, 0, stream>>>(hist, bbase, start);
    scatter_kernel<<<EBLK, 256, 0, stream>>>(ei, start, epack);
    csr_compact_kernel<<<NBKT * 4, 256, 0, stream>>>(epack, bbase, off, srcs);

    const int pblk = (NN + 63) / 64;
    const int nblk = (NN + 255) / 256;
    const int gblk = (NN * 4 + 255) / 256;

    // layer 0 (F_IN=128, no input BN)
    proj_kernel<128><<<pblk, 256, 0, stream>>>(x, w1_0, nullptr, nullptr, nullptr, q4);
    gather_kernel<<<gblk, 256, 0, stream>>>(q4, srcs, off, b1_0, agg);
    mlp_kernel<<<nblk, 256, 0, stream>>>(agg, w2_0, b2_0, h, stats);

    // layers 1..3, prev BN computed in proj from raw stats slot
    for (int i = 0; i < 3; i++) {
        const float* st_prev = stats + i * 64;
        proj_kernel<32><<<pblk, 256, 0, stream>>>(h, w1s + i * 1024, st_prev,
                                                  gs + i * 32, bes + i * 32, q4);
        gather_kernel<<<gblk, 256, 0, stream>>>(q4, srcs, off, b1s + i * 32, agg);
        mlp_kernel<<<nblk, 256, 0, stream>>>(agg, w2s + i * 1024, b2s + i * 32, h,
                                             stats + (i + 1) * 64);
    }

    int pthreads = ((NN + PR - 1) / PR) * 32;
    pool_kernel<<<(pthreads + 255) / 256, 256, 0, stream>>>(h, batch, pooled, pcnt);
    head_kernel<<<1, 128, 0, stream>>>(pooled, pcnt, stats + 3 * 64, gs + 2 * 32,
                                       bes + 2 * 32, fc1w, fc1b, fc2w, fc2b, out);
}